// Round 8
// baseline (132.146 us; speedup 1.0000x reference)
//
#include <hip/hip_runtime.h>

typedef short short8 __attribute__((ext_vector_type(8)));
typedef short short4v __attribute__((ext_vector_type(4)));
typedef float f32x4 __attribute__((ext_vector_type(4)));
typedef float float4v __attribute__((ext_vector_type(4)));
typedef int int4v __attribute__((ext_vector_type(4)));
typedef int int2v __attribute__((ext_vector_type(2)));

__device__ __forceinline__ short f2bf(float f) {
  union { float f; unsigned u; } v; v.f = f;
  unsigned r = v.u + 0x7FFFu + ((v.u >> 16) & 1u);
  return (short)(r >> 16);
}

__device__ __forceinline__ unsigned cvtpk_bf16(float lo, float hi) {
  unsigned r;
  asm("v_cvt_pk_bf16_f32 %0, %1, %2" : "=v"(r) : "v"(lo), "v"(hi));
  return r;  // lo16 = bf16(lo), hi16 = bf16(hi)
}

// async global->LDS, 16B per lane; dest must be linear (wave base + lane*16)
#define GLD16(gp, lp)                                                   \
  __builtin_amdgcn_global_load_lds(                                     \
      (const __attribute__((address_space(1))) void*)(gp),              \
      (__attribute__((address_space(3))) void*)(lp), 16, 0, 0)

// Q scale: softmax uses exp2, so fold log2(e) into the 1/sqrt(64) scale
#define QSCALE 0.18033688011112042f

// ---------------- fused fp32 -> bf16 convert (x | w_qkv | w_proj) ----------------
__global__ __launch_bounds__(256) void cvt_all(
    const float* __restrict__ x, const float* __restrict__ wq, const float* __restrict__ wp,
    short* __restrict__ xb, short* __restrict__ wqb, short* __restrict__ wpb) {
  int i = blockIdx.x * 256 + threadIdx.x;  // in float4 units; total 2097152
  const float* s; short* d; int off;
  if (i < 1048576)      { s = x;  d = xb;  off = i; }
  else if (i < 1835008) { s = wq; d = wqb; off = i - 1048576; }
  else                  { s = wp; d = wpb; off = i - 1835008; }
  float4v v = ((const float4v*)s)[off];
  short4v o;
  o.x = f2bf(v.x); o.y = f2bf(v.y); o.z = f2bf(v.z); o.w = f2bf(v.w);
  ((short4v*)d)[off] = o;
}

// ---------------- GEMM: C[M,Ncols] = A[M,1024] @ Bw[Ncols,1024]^T + bias ----------------
// Double-buffered LDS; prefetch issued after the barrier.
template <int MODE>
__global__ __launch_bounds__(256) void gemm_bt(
    const short* __restrict__ A, const short* __restrict__ Bw,
    const float* __restrict__ bias,
    short* __restrict__ qo, short* __restrict__ ko, short* __restrict__ vto,
    float* __restrict__ outf) {
  __shared__ short As[2][128 * 64];
  __shared__ short Bs[2][128 * 64];
  const int t = threadIdx.x;
  const int lane = t & 63, wid = t >> 6;
  const int g = lane >> 4, l15 = lane & 15;
  const int wr = (wid >> 1) * 64, wc = (wid & 1) * 64;
  const int bm0 = blockIdx.y * 128, bn0 = blockIdx.x * 128;

  const int sr = t >> 3;
  const int ssub0 = t & 7;

  // LICM: swizzled fragment offsets (row&7 == l15&7 -> uniform swizzle term)
  const int swz = (l15 & 7) << 4;
  int aoff[2][4], boff[2][4];
#pragma unroll
  for (int kk = 0; kk < 2; ++kk)
#pragma unroll
    for (int f = 0; f < 4; ++f) {
      aoff[kk][f] = ((wr + f * 16 + l15) * 128 + kk * 64 + g * 16) ^ swz;
      boff[kk][f] = ((wc + f * 16 + l15) * 128 + kk * 64 + g * 16) ^ swz;
    }

  f32x4 acc[4][4] = {};

  auto stage = [&](int buf, int k0) {
#pragma unroll
    for (int i = 0; i < 4; ++i) {
      int row = i * 32 + sr;
      int s = ssub0 ^ (row & 7);
      char* ldsA = (char*)&As[buf][0] + (i * 256 + (t & ~63)) * 16;
      char* ldsB = (char*)&Bs[buf][0] + (i * 256 + (t & ~63)) * 16;
      GLD16(A + (size_t)(bm0 + row) * 1024 + k0 + s * 8, ldsA);
      GLD16(Bw + (size_t)(bn0 + row) * 1024 + k0 + s * 8, ldsB);
    }
  };

  stage(0, 0);  // prefetch K-tile 0
  int curOff = 0;

  for (int it = 0; it < 16; ++it) {
    __syncthreads();  // tile `it` staged; prior reads of other buffer done
    if (it + 1 < 16) stage((it + 1) & 1, (it + 1) * 64);
    const char* AsB = (const char*)&As[0][0] + curOff;
    const char* BsB = (const char*)&Bs[0][0] + curOff;
    curOff ^= 16384;  // bytes per buffer (128*64*2)
#pragma unroll
    for (int kk = 0; kk < 2; ++kk) {
      short8 a[4], b[4];
#pragma unroll
      for (int mi = 0; mi < 4; ++mi) a[mi] = *(const short8*)(AsB + aoff[kk][mi]);
#pragma unroll
      for (int ni = 0; ni < 4; ++ni) b[ni] = *(const short8*)(BsB + boff[kk][ni]);
#pragma unroll
      for (int mi = 0; mi < 4; ++mi)
#pragma unroll
        for (int ni = 0; ni < 4; ++ni)
          acc[mi][ni] = __builtin_amdgcn_mfma_f32_16x16x32_bf16(a[mi], b[ni], acc[mi][ni], 0, 0, 0);
    }
  }

  if constexpr (MODE == 0) {
    const int which = bn0 >> 10;  // block-uniform: 0=Q, 1=K, 2=V
    if (which == 2) {
      // V^T permuted store, vectorized: 4 consecutive n in-lane -> 8B stores
#pragma unroll
      for (int mi = 0; mi < 4; ++mi) {
#pragma unroll
        for (int ni = 0; ni < 4; ++ni) {
          int gcol = bn0 + wc + ni * 16 + l15;
          int w1 = gcol & 1023;
          int h = w1 >> 6, dd = w1 & 63;
          float bv = bias[gcol];
          int grow0 = bm0 + wr + mi * 16 + g * 4;
          int b_ = grow0 >> 11, n0 = grow0 & 2047;
          int bh = b_ * 16 + h;
          int nl = n0 & 63;
          // kv bit-perm [b5][b3][b2][b4][b1][b0]; n0 4-aligned -> np0 too
          int np = (n0 & ~63) | (nl & 32) | ((nl & 12) << 1) | ((nl & 16) >> 2);
          int2v pk;
          pk.x = (int)cvtpk_bf16(acc[mi][ni][0] + bv, acc[mi][ni][1] + bv);
          pk.y = (int)cvtpk_bf16(acc[mi][ni][2] + bv, acc[mi][ni][3] + bv);
          *(int2v*)(vto + ((size_t)bh * 64 + dd) * 2048 + np) = pk;
        }
      }
    } else {
      short* dst = (which == 0) ? qo : ko;
      const float sc = (which == 0) ? QSCALE : 1.0f;
#pragma unroll
      for (int mi = 0; mi < 4; ++mi) {
#pragma unroll
        for (int ni = 0; ni < 4; ++ni) {
          int gcol = bn0 + wc + ni * 16 + l15;
          int w1 = gcol & 1023;
          int h = w1 >> 6, dd = w1 & 63;
          float bv = bias[gcol];
#pragma unroll
          for (int r = 0; r < 4; ++r) {
            int grow = bm0 + wr + mi * 16 + g * 4 + r;
            int b_ = grow >> 11, n = grow & 2047;
            int bh = b_ * 16 + h;
            dst[((size_t)bh * 2048 + n) * 64 + dd] = f2bf((acc[mi][ni][r] + bv) * sc);
          }
        }
      }
    }
  } else {
#pragma unroll
    for (int mi = 0; mi < 4; ++mi) {
#pragma unroll
      for (int ni = 0; ni < 4; ++ni) {
        int gcol = bn0 + wc + ni * 16 + l15;
        float bv = bias[gcol];
#pragma unroll
        for (int r = 0; r < 4; ++r) {
          int grow = bm0 + wr + mi * 16 + g * 4 + r;
          outf[(size_t)grow * 1024 + gcol] = acc[mi][ni][r] + bv;
        }
      }
    }
  }
}

// ---------------- flash attention, swapped-operand, zero-shuffle PV ----------------
// 4 waves x 16 q-rows = 64 q-rows per block -> grid 1024 = 4 blocks/CU
// (4 waves/SIMD). bh = bid&31 keeps XCD affinity (bid%8 == bh%8).
// Row-sum via scalar lrun + shuffle reduce (proven path; MFMA ones-trick
// from R7 produced wrong 1/l on HW -> reverted, do not retry).
__global__ __launch_bounds__(256, 4) void attn_fused(
    const short* __restrict__ Qg, const short* __restrict__ Kg,
    const short* __restrict__ Vtg, short* __restrict__ AO) {
  __shared__ short Ks[2][64 * 64];
  __shared__ short Vs[2][64 * 64];
  const int bid = blockIdx.x;
  const int bh = bid & 31, qt = bid >> 5;
  const int t = threadIdx.x, wid = t >> 6, lane = t & 63;
  const int g = lane >> 4, l15 = lane & 15;
  const int q0w = qt * 64 + wid * 16;
  const short* qb = Qg + ((size_t)bh * 2048 + q0w) * 64;
  const short* kb = Kg + (size_t)bh * 2048 * 64;
  const short* vb = Vtg + (size_t)bh * 64 * 2048;

  // staging: 256 threads x 16B = 4KB per batch, 2 batches per 8KB tile.
  // linear LDS dest, pre-swizzled global source (rule 21).
  const int srow = t >> 3;
  const int ssub = (t & 7) ^ (srow & 7);
  const short* ksrc0 = kb + srow * 64 + ssub * 8;
  const short* vsrc0 = vb + (size_t)srow * 2048 + ssub * 8;

  // LICM: swizzled fragment offsets, shared by K and V reads
  const int swz = (l15 & 7) << 4;
  int foff[2][4];
#pragma unroll
  for (int kk = 0; kk < 2; ++kk)
#pragma unroll
    for (int f = 0; f < 4; ++f)
      foff[kk][f] = ((f * 16 + l15) * 128 + kk * 64 + g * 16) ^ swz;

  short8 bq[2];
#pragma unroll
  for (int kk = 0; kk < 2; ++kk)
    bq[kk] = *(const short8*)(qb + l15 * 64 + kk * 32 + g * 8);

  // prefetch tile 0
#pragma unroll
  for (int i = 0; i < 2; ++i) {
    GLD16(ksrc0 + i * 32 * 64,           (char*)&Ks[0][0] + i * 4096 + wid * 1024);
    GLD16(vsrc0 + (size_t)i * 32 * 2048, (char*)&Vs[0][0] + i * 4096 + wid * 1024);
  }

  f32x4 acc[4] = {};
  float mrun = -3.0e38f, lrun = 0.f;
  int curOff = 0;

  for (int it = 0; it < 32; ++it) {
    __syncthreads();  // tile `it` staged; prior reads of other buffer done
    if (it + 1 < 32) {
      const int n1 = (it + 1) * 64;
      char* ldsK = (char*)&Ks[(it + 1) & 1][0] + wid * 1024;
      char* ldsV = (char*)&Vs[(it + 1) & 1][0] + wid * 1024;
#pragma unroll
      for (int i = 0; i < 2; ++i) {
        GLD16(ksrc0 + (size_t)(n1 + i * 32) * 64, ldsK + i * 4096);
        GLD16(vsrc0 + (size_t)i * 32 * 2048 + n1, ldsV + i * 4096);
      }
    }
    const char* KsB = (const char*)&Ks[0][0] + curOff;
    const char* VsB = (const char*)&Vs[0][0] + curOff;
    curOff ^= 8192;

    // S^T[kv][q]: s[kf], kv = kf*16 + g*4 + r, q = l15
    f32x4 s[4] = {};
#pragma unroll
    for (int kk = 0; kk < 2; ++kk) {
      short8 ak[4];
#pragma unroll
      for (int kf = 0; kf < 4; ++kf) ak[kf] = *(const short8*)(KsB + foff[kk][kf]);
#pragma unroll
      for (int kf = 0; kf < 4; ++kf)
        s[kf] = __builtin_amdgcn_mfma_f32_16x16x32_bf16(ak[kf], bq[kk], s[kf], 0, 0, 0);
    }

    // tile max (lane-local chain + 2 cross-group reduces)
    float m0 = fmaxf(s[0][0], s[0][1]);
    m0 = fmaxf(fmaxf(m0, s[0][2]), s[0][3]);
#pragma unroll
    for (int kf = 1; kf < 4; ++kf) {
      m0 = fmaxf(fmaxf(m0, s[kf][0]), s[kf][1]);
      m0 = fmaxf(fmaxf(m0, s[kf][2]), s[kf][3]);
    }
    float pm = fmaxf(m0, __shfl_xor(m0, 16));
    pm = fmaxf(pm, __shfl_xor(pm, 32));

    // defer-max (T13): rescale only when the max grew by > 8 (exp2 domain)
    if (!__all(pm - mrun <= 8.f)) {
      float mn = fmaxf(mrun, pm);
      float alpha = __builtin_amdgcn_exp2f(mrun - mn);
      mrun = mn;
      lrun *= alpha;
#pragma unroll
      for (int df = 0; df < 4; ++df)
#pragma unroll
        for (int r = 0; r < 4; ++r) acc[df][r] *= alpha;
    }

    // P = exp2(S - m), row sum, pack to bf16 pairs (lane-local)
    float rs = 0.f;
    unsigned wpk[4][2];
#pragma unroll
    for (int kf = 0; kf < 4; ++kf) {
      float p0 = __builtin_amdgcn_exp2f(s[kf][0] - mrun);
      float p1 = __builtin_amdgcn_exp2f(s[kf][1] - mrun);
      float p2 = __builtin_amdgcn_exp2f(s[kf][2] - mrun);
      float p3 = __builtin_amdgcn_exp2f(s[kf][3] - mrun);
      rs += (p0 + p1) + (p2 + p3);
      wpk[kf][0] = cvtpk_bf16(p0, p1);
      wpk[kf][1] = cvtpk_bf16(p2, p3);
    }
    rs += __shfl_xor(rs, 16);
    rs += __shfl_xor(rs, 32);
    lrun += rs;

    // O^T += V^T_perm @ P^T — B operand is the lane's own packed words
#pragma unroll
    for (int kk = 0; kk < 2; ++kk) {
      short8 av[4];
#pragma unroll
      for (int df = 0; df < 4; ++df) av[df] = *(const short8*)(VsB + foff[kk][df]);
      union { int4v i; short8 s; } pv;
      pv.i[0] = (int)wpk[2 * kk][0];
      pv.i[1] = (int)wpk[2 * kk][1];
      pv.i[2] = (int)wpk[2 * kk + 1][0];
      pv.i[3] = (int)wpk[2 * kk + 1][1];
#pragma unroll
      for (int df = 0; df < 4; ++df)
        acc[df] = __builtin_amdgcn_mfma_f32_16x16x32_bf16(av[df], pv.s, acc[df], 0, 0, 0);
    }
  }

  // O^T fragments: d = df*16 + g*4 + r, q = q0w + l15
  const int b_ = bh >> 4, h = bh & 15;
  const float inv = 1.0f / lrun;
  short* outp = AO + ((size_t)b_ * 2048 + q0w + l15) * 1024 + h * 64 + g * 4;
#pragma unroll
  for (int df = 0; df < 4; ++df) {
    short4v o;
#pragma unroll
    for (int r = 0; r < 4; ++r) o[r] = f2bf(acc[df][r] * inv);
    *(short4v*)(outp + df * 16) = o;
  }
}

// ---------------- launch ----------------
extern "C" void kernel_launch(void* const* d_in, const int* in_sizes, int n_in,
                              void* d_out, int out_size, void* d_ws, size_t ws_size,
                              hipStream_t stream) {
  const float* x = (const float*)d_in[0];
  const float* w_qkv = (const float*)d_in[1];
  const float* b_qkv = (const float*)d_in[2];
  const float* w_proj = (const float*)d_in[3];
  const float* b_proj = (const float*)d_in[4];
  float* out = (float*)d_out;
  char* ws = (char*)d_ws;

  short* xb    = (short*)(ws + (size_t)0);
  short* wqkvb = (short*)(ws + ((size_t)8 << 20));
  short* wprojb= (short*)(ws + ((size_t)14 << 20));
  short* qb    = (short*)(ws + ((size_t)16 << 20));
  short* kb    = (short*)(ws + ((size_t)24 << 20));
  short* vtb   = (short*)(ws + ((size_t)32 << 20));
  short* aob   = (short*)(ws + ((size_t)40 << 20));

  cvt_all<<<8192, 256, 0, stream>>>(x, w_qkv, w_proj, xb, wqkvb, wprojb);
  gemm_bt<0><<<dim3(24, 32), 256, 0, stream>>>(xb, wqkvb, b_qkv, qb, kb, vtb, nullptr);
  attn_fused<<<1024, 256, 0, stream>>>(qb, kb, vtb, aob);
  gemm_bt<1><<<dim3(8, 32), 256, 0, stream>>>(aob, wprojb, b_proj, nullptr, nullptr, nullptr, out);
}

// Round 9
// 123.242 us; speedup vs baseline: 1.0723x; 1.0723x over previous
//
#include <hip/hip_runtime.h>

typedef short short8 __attribute__((ext_vector_type(8)));
typedef short short4v __attribute__((ext_vector_type(4)));
typedef float f32x4 __attribute__((ext_vector_type(4)));
typedef float float4v __attribute__((ext_vector_type(4)));
typedef int int4v __attribute__((ext_vector_type(4)));
typedef int int2v __attribute__((ext_vector_type(2)));

__device__ __forceinline__ short f2bf(float f) {
  union { float f; unsigned u; } v; v.f = f;
  unsigned r = v.u + 0x7FFFu + ((v.u >> 16) & 1u);
  return (short)(r >> 16);
}

__device__ __forceinline__ unsigned cvtpk_bf16(float lo, float hi) {
  unsigned r;
  asm("v_cvt_pk_bf16_f32 %0, %1, %2" : "=v"(r) : "v"(lo), "v"(hi));
  return r;  // lo16 = bf16(lo), hi16 = bf16(hi)
}

// async global->LDS, 16B per lane; dest must be linear (wave base + lane*16)
#define GLD16(gp, lp)                                                   \
  __builtin_amdgcn_global_load_lds(                                     \
      (const __attribute__((address_space(1))) void*)(gp),              \
      (__attribute__((address_space(3))) void*)(lp), 16, 0, 0)

// Q scale: softmax uses exp2, so fold log2(e) into the 1/sqrt(64) scale
#define QSCALE 0.18033688011112042f

// ---------------- fused fp32 -> bf16 convert (x | w_qkv | w_proj) ----------------
__global__ __launch_bounds__(256) void cvt_all(
    const float* __restrict__ x, const float* __restrict__ wq, const float* __restrict__ wp,
    short* __restrict__ xb, short* __restrict__ wqb, short* __restrict__ wpb) {
  int i = blockIdx.x * 256 + threadIdx.x;  // in float4 units; total 2097152
  const float* s; short* d; int off;
  if (i < 1048576)      { s = x;  d = xb;  off = i; }
  else if (i < 1835008) { s = wq; d = wqb; off = i - 1048576; }
  else                  { s = wp; d = wpb; off = i - 1835008; }
  float4v v = ((const float4v*)s)[off];
  short4v o;
  o.x = f2bf(v.x); o.y = f2bf(v.y); o.z = f2bf(v.z); o.w = f2bf(v.w);
  ((short4v*)d)[off] = o;
}

// ---------------- GEMM: C[M,Ncols] = A[M,1024] @ Bw[Ncols,1024]^T + bias ----------------
// Depth-2 prefetch with counted vmcnt (T4): raw s_barriers, never drain the
// in-flight next-tile loads. stage(it+2) overwrites the buffer read at iter
// it, separated by the post-compute barrier.
template <int MODE>
__global__ __launch_bounds__(256) void gemm_bt(
    const short* __restrict__ A, const short* __restrict__ Bw,
    const float* __restrict__ bias,
    short* __restrict__ qo, short* __restrict__ ko, short* __restrict__ vto,
    float* __restrict__ outf) {
  __shared__ short As[2][128 * 64];
  __shared__ short Bs[2][128 * 64];
  const int t = threadIdx.x;
  const int lane = t & 63, wid = t >> 6;
  const int g = lane >> 4, l15 = lane & 15;
  const int wr = (wid >> 1) * 64, wc = (wid & 1) * 64;
  const int bm0 = blockIdx.y * 128, bn0 = blockIdx.x * 128;

  const int sr = t >> 3;
  const int ssub0 = t & 7;

  // LICM: swizzled fragment offsets (row&7 == l15&7 -> uniform swizzle term)
  const int swz = (l15 & 7) << 4;
  int aoff[2][4], boff[2][4];
#pragma unroll
  for (int kk = 0; kk < 2; ++kk)
#pragma unroll
    for (int f = 0; f < 4; ++f) {
      aoff[kk][f] = ((wr + f * 16 + l15) * 128 + kk * 64 + g * 16) ^ swz;
      boff[kk][f] = ((wc + f * 16 + l15) * 128 + kk * 64 + g * 16) ^ swz;
    }

  f32x4 acc[4][4] = {};

  auto stage = [&](int buf, int k0) {
#pragma unroll
    for (int i = 0; i < 4; ++i) {
      int row = i * 32 + sr;
      int s = ssub0 ^ (row & 7);
      char* ldsA = (char*)&As[buf][0] + (i * 256 + (t & ~63)) * 16;
      char* ldsB = (char*)&Bs[buf][0] + (i * 256 + (t & ~63)) * 16;
      GLD16(A + (size_t)(bm0 + row) * 1024 + k0 + s * 8, ldsA);
      GLD16(Bw + (size_t)(bn0 + row) * 1024 + k0 + s * 8, ldsB);
    }
  };

  stage(0, 0);    // prefetch K-tile 0 (8 loads)
  stage(1, 64);   // prefetch K-tile 1 (8 more; 16 in flight)
  int curOff = 0;

  for (int it = 0; it < 16; ++it) {
    // wait for THIS tile's 8 loads (oldest in FIFO); keep next tile's in flight
    if (it == 15) asm volatile("s_waitcnt vmcnt(0)" ::: "memory");
    else          asm volatile("s_waitcnt vmcnt(8)" ::: "memory");
    __builtin_amdgcn_s_barrier();          // all waves: tile `it` ready
    __builtin_amdgcn_sched_barrier(0);
    const char* AsB = (const char*)&As[0][0] + curOff;
    const char* BsB = (const char*)&Bs[0][0] + curOff;
#pragma unroll
    for (int kk = 0; kk < 2; ++kk) {
      short8 a[4], b[4];
#pragma unroll
      for (int mi = 0; mi < 4; ++mi) a[mi] = *(const short8*)(AsB + aoff[kk][mi]);
#pragma unroll
      for (int ni = 0; ni < 4; ++ni) b[ni] = *(const short8*)(BsB + boff[kk][ni]);
#pragma unroll
      for (int mi = 0; mi < 4; ++mi)
#pragma unroll
        for (int ni = 0; ni < 4; ++ni)
          acc[mi][ni] = __builtin_amdgcn_mfma_f32_16x16x32_bf16(a[mi], b[ni], acc[mi][ni], 0, 0, 0);
    }
    __builtin_amdgcn_sched_barrier(0);     // pin all reads before the barrier
    __builtin_amdgcn_s_barrier();          // all waves done reading this buffer
    __builtin_amdgcn_sched_barrier(0);     // pin stage after the barrier
    if (it + 2 < 16) stage(it & 1, (it + 2) * 64);  // (it+2)&1 == it&1
    curOff ^= 16384;  // bytes per buffer (128*64*2)
  }

  if constexpr (MODE == 0) {
    const int which = bn0 >> 10;  // block-uniform: 0=Q, 1=K, 2=V
    if (which == 2) {
      // V^T permuted store, vectorized: 4 consecutive n in-lane -> 8B stores
#pragma unroll
      for (int mi = 0; mi < 4; ++mi) {
#pragma unroll
        for (int ni = 0; ni < 4; ++ni) {
          int gcol = bn0 + wc + ni * 16 + l15;
          int w1 = gcol & 1023;
          int h = w1 >> 6, dd = w1 & 63;
          float bv = bias[gcol];
          int grow0 = bm0 + wr + mi * 16 + g * 4;
          int b_ = grow0 >> 11, n0 = grow0 & 2047;
          int bh = b_ * 16 + h;
          int nl = n0 & 63;
          // kv bit-perm [b5][b3][b2][b4][b1][b0]; n0 4-aligned -> np0 too
          int np = (n0 & ~63) | (nl & 32) | ((nl & 12) << 1) | ((nl & 16) >> 2);
          int2v pk;
          pk.x = (int)cvtpk_bf16(acc[mi][ni][0] + bv, acc[mi][ni][1] + bv);
          pk.y = (int)cvtpk_bf16(acc[mi][ni][2] + bv, acc[mi][ni][3] + bv);
          *(int2v*)(vto + ((size_t)bh * 64 + dd) * 2048 + np) = pk;
        }
      }
    } else {
      short* dst = (which == 0) ? qo : ko;
      const float sc = (which == 0) ? QSCALE : 1.0f;
#pragma unroll
      for (int mi = 0; mi < 4; ++mi) {
#pragma unroll
        for (int ni = 0; ni < 4; ++ni) {
          int gcol = bn0 + wc + ni * 16 + l15;
          int w1 = gcol & 1023;
          int h = w1 >> 6, dd = w1 & 63;
          float bv = bias[gcol];
#pragma unroll
          for (int r = 0; r < 4; ++r) {
            int grow = bm0 + wr + mi * 16 + g * 4 + r;
            int b_ = grow >> 11, n = grow & 2047;
            int bh = b_ * 16 + h;
            dst[((size_t)bh * 2048 + n) * 64 + dd] = f2bf((acc[mi][ni][r] + bv) * sc);
          }
        }
      }
    }
  } else {
#pragma unroll
    for (int mi = 0; mi < 4; ++mi) {
#pragma unroll
      for (int ni = 0; ni < 4; ++ni) {
        int gcol = bn0 + wc + ni * 16 + l15;
        float bv = bias[gcol];
#pragma unroll
        for (int r = 0; r < 4; ++r) {
          int grow = bm0 + wr + mi * 16 + g * 4 + r;
          outf[(size_t)grow * 1024 + gcol] = acc[mi][ni][r] + bv;
        }
      }
    }
  }
}

// ---------------- flash attention, swapped-operand, zero-shuffle PV ----------------
// R6 config (proven 60.0us): 4 waves x 32 q-rows = 128 q-rows/block, grid 512
// = 2 blocks/CU. bh = bid&31 keeps XCD affinity. R8's 16-rows/wave variant
// doubled DS-pipe time per work -> 65.6us; do not retry.
__global__ __launch_bounds__(256, 2) void attn_fused(
    const short* __restrict__ Qg, const short* __restrict__ Kg,
    const short* __restrict__ Vtg, short* __restrict__ AO) {
  __shared__ short Ks[2][64 * 64];
  __shared__ short Vs[2][64 * 64];
  const int bid = blockIdx.x;
  const int bh = bid & 31, qt = bid >> 5;
  const int t = threadIdx.x, wid = t >> 6, lane = t & 63;
  const int g = lane >> 4, l15 = lane & 15;
  const int q0w = qt * 128 + wid * 32;
  const short* qb = Qg + ((size_t)bh * 2048 + q0w) * 64;
  const short* kb = Kg + (size_t)bh * 2048 * 64;
  const short* vb = Vtg + (size_t)bh * 64 * 2048;

  // staging: 256 threads x 16B = 4KB per batch, 2 batches per 8KB tile.
  // linear LDS dest, pre-swizzled global source (rule 21).
  const int srow = t >> 3;
  const int ssub = (t & 7) ^ (srow & 7);
  const short* ksrc0 = kb + srow * 64 + ssub * 8;
  const short* vsrc0 = vb + (size_t)srow * 2048 + ssub * 8;

  // LICM: swizzled fragment offsets, shared by K and V reads
  const int swz = (l15 & 7) << 4;
  int foff[2][4];
#pragma unroll
  for (int kk = 0; kk < 2; ++kk)
#pragma unroll
    for (int f = 0; f < 4; ++f)
      foff[kk][f] = ((f * 16 + l15) * 128 + kk * 64 + g * 16) ^ swz;

  short8 bq[2][2];
#pragma unroll
  for (int qf = 0; qf < 2; ++qf)
#pragma unroll
    for (int kk = 0; kk < 2; ++kk)
      bq[qf][kk] = *(const short8*)(qb + (qf * 16 + l15) * 64 + kk * 32 + g * 8);

  // prefetch tile 0
#pragma unroll
  for (int i = 0; i < 2; ++i) {
    GLD16(ksrc0 + i * 32 * 64,           (char*)&Ks[0][0] + i * 4096 + wid * 1024);
    GLD16(vsrc0 + (size_t)i * 32 * 2048, (char*)&Vs[0][0] + i * 4096 + wid * 1024);
  }

  f32x4 acc[2][4] = {};
  float mrun[2] = {-3.0e38f, -3.0e38f}, lrun[2] = {0.f, 0.f};
  int curOff = 0;

  for (int it = 0; it < 32; ++it) {
    __syncthreads();  // tile `it` staged; prior reads of other buffer done
    if (it + 1 < 32) {
      const int n1 = (it + 1) * 64;
      char* ldsK = (char*)&Ks[(it + 1) & 1][0] + wid * 1024;
      char* ldsV = (char*)&Vs[(it + 1) & 1][0] + wid * 1024;
#pragma unroll
      for (int i = 0; i < 2; ++i) {
        GLD16(ksrc0 + (size_t)(n1 + i * 32) * 64, ldsK + i * 4096);
        GLD16(vsrc0 + (size_t)i * 32 * 2048 + n1, ldsV + i * 4096);
      }
    }
    const char* KsB = (const char*)&Ks[0][0] + curOff;
    const char* VsB = (const char*)&Vs[0][0] + curOff;
    curOff ^= 8192;

    // S^T[kv][q]: s[qf][kf], kv = kf*16 + g*4 + r, q = qf*16 + l15
    f32x4 s[2][4] = {};
#pragma unroll
    for (int kk = 0; kk < 2; ++kk) {
      short8 ak[4];
#pragma unroll
      for (int kf = 0; kf < 4; ++kf) ak[kf] = *(const short8*)(KsB + foff[kk][kf]);
#pragma unroll
      for (int kf = 0; kf < 4; ++kf)
#pragma unroll
        for (int qf = 0; qf < 2; ++qf)
          s[qf][kf] = __builtin_amdgcn_mfma_f32_16x16x32_bf16(ak[kf], bq[qf][kk], s[qf][kf], 0, 0, 0);
    }

    // tile max per qf (max3-friendly chains + 2 cross-group reduces)
    float pm[2];
#pragma unroll
    for (int qf = 0; qf < 2; ++qf) {
      float m0 = fmaxf(s[qf][0][0], s[qf][0][1]);
      m0 = fmaxf(fmaxf(m0, s[qf][0][2]), s[qf][0][3]);
#pragma unroll
      for (int kf = 1; kf < 4; ++kf) {
        m0 = fmaxf(fmaxf(m0, s[qf][kf][0]), s[qf][kf][1]);
        m0 = fmaxf(fmaxf(m0, s[qf][kf][2]), s[qf][kf][3]);
      }
      float x = fmaxf(m0, __shfl_xor(m0, 16));
      pm[qf] = fmaxf(x, __shfl_xor(x, 32));
    }

    // defer-max (T13): rescale only when a max grew by > 8 (exp2 domain)
    if (!__all((pm[0] - mrun[0] <= 8.f) && (pm[1] - mrun[1] <= 8.f))) {
#pragma unroll
      for (int qf = 0; qf < 2; ++qf) {
        float mn = fmaxf(mrun[qf], pm[qf]);
        float alpha = __builtin_amdgcn_exp2f(mrun[qf] - mn);
        mrun[qf] = mn;
        lrun[qf] *= alpha;
#pragma unroll
        for (int df = 0; df < 4; ++df)
#pragma unroll
          for (int r = 0; r < 4; ++r) acc[qf][df][r] *= alpha;
      }
    }

    // P = exp2(S - m), row sums, pack to bf16 pairs (lane-local)
    unsigned wpk[2][4][2];
#pragma unroll
    for (int qf = 0; qf < 2; ++qf) {
      float rs = 0.f;
      float p[4][4];
#pragma unroll
      for (int kf = 0; kf < 4; ++kf)
#pragma unroll
        for (int r = 0; r < 4; ++r) {
          p[kf][r] = __builtin_amdgcn_exp2f(s[qf][kf][r] - mrun[qf]);
          rs += p[kf][r];
        }
      rs += __shfl_xor(rs, 16);
      rs += __shfl_xor(rs, 32);
      lrun[qf] += rs;
#pragma unroll
      for (int kf = 0; kf < 4; ++kf)
#pragma unroll
        for (int h = 0; h < 2; ++h)
          wpk[qf][kf][h] = cvtpk_bf16(p[kf][2 * h], p[kf][2 * h + 1]);
    }

    // O^T += V^T_perm @ P^T — B operand is the lane's own packed words
#pragma unroll
    for (int kk = 0; kk < 2; ++kk) {
      short8 av[4];
#pragma unroll
      for (int df = 0; df < 4; ++df) av[df] = *(const short8*)(VsB + foff[kk][df]);
#pragma unroll
      for (int qf = 0; qf < 2; ++qf) {
        union { int4v i; short8 s; } pv;
        pv.i[0] = (int)wpk[qf][2 * kk][0];
        pv.i[1] = (int)wpk[qf][2 * kk][1];
        pv.i[2] = (int)wpk[qf][2 * kk + 1][0];
        pv.i[3] = (int)wpk[qf][2 * kk + 1][1];
#pragma unroll
        for (int df = 0; df < 4; ++df)
          acc[qf][df] = __builtin_amdgcn_mfma_f32_16x16x32_bf16(av[df], pv.s, acc[qf][df], 0, 0, 0);
      }
    }
  }

  // O^T fragments: d = df*16 + g*4 + r, q = q0w + qf*16 + l15
  const int b_ = bh >> 4, h = bh & 15;
#pragma unroll
  for (int qf = 0; qf < 2; ++qf) {
    const float inv = 1.0f / lrun[qf];
    short* outp = AO + ((size_t)b_ * 2048 + q0w + qf * 16 + l15) * 1024 + h * 64 + g * 4;
#pragma unroll
    for (int df = 0; df < 4; ++df) {
      short4v o;
#pragma unroll
      for (int r = 0; r < 4; ++r) o[r] = f2bf(acc[qf][df][r] * inv);
      *(short4v*)(outp + df * 16) = o;
    }
  }
}

// ---------------- launch ----------------
extern "C" void kernel_launch(void* const* d_in, const int* in_sizes, int n_in,
                              void* d_out, int out_size, void* d_ws, size_t ws_size,
                              hipStream_t stream) {
  const float* x = (const float*)d_in[0];
  const float* w_qkv = (const float*)d_in[1];
  const float* b_qkv = (const float*)d_in[2];
  const float* w_proj = (const float*)d_in[3];
  const float* b_proj = (const float*)d_in[4];
  float* out = (float*)d_out;
  char* ws = (char*)d_ws;

  short* xb    = (short*)(ws + (size_t)0);
  short* wqkvb = (short*)(ws + ((size_t)8 << 20));
  short* wprojb= (short*)(ws + ((size_t)14 << 20));
  short* qb    = (short*)(ws + ((size_t)16 << 20));
  short* kb    = (short*)(ws + ((size_t)24 << 20));
  short* vtb   = (short*)(ws + ((size_t)32 << 20));
  short* aob   = (short*)(ws + ((size_t)40 << 20));

  cvt_all<<<8192, 256, 0, stream>>>(x, w_qkv, w_proj, xb, wqkvb, wprojb);
  gemm_bt<0><<<dim3(24, 32), 256, 0, stream>>>(xb, wqkvb, b_qkv, qb, kb, vtb, nullptr);
  attn_fused<<<512, 256, 0, stream>>>(qb, kb, vtb, aob);
  gemm_bt<1><<<dim3(8, 32), 256, 0, stream>>>(aob, wprojb, b_proj, nullptr, nullptr, nullptr, out);
}

// Round 10
// 122.414 us; speedup vs baseline: 1.0795x; 1.0068x over previous
//
#include <hip/hip_runtime.h>

typedef short short8 __attribute__((ext_vector_type(8)));
typedef short short4v __attribute__((ext_vector_type(4)));
typedef float f32x4 __attribute__((ext_vector_type(4)));
typedef float float4v __attribute__((ext_vector_type(4)));
typedef int int4v __attribute__((ext_vector_type(4)));
typedef int int2v __attribute__((ext_vector_type(2)));

__device__ __forceinline__ short f2bf(float f) {
  union { float f; unsigned u; } v; v.f = f;
  unsigned r = v.u + 0x7FFFu + ((v.u >> 16) & 1u);
  return (short)(r >> 16);
}

__device__ __forceinline__ unsigned cvtpk_bf16(float lo, float hi) {
  unsigned r;
  asm("v_cvt_pk_bf16_f32 %0, %1, %2" : "=v"(r) : "v"(lo), "v"(hi));
  return r;  // lo16 = bf16(lo), hi16 = bf16(hi)
}

// async global->LDS, 16B per lane; dest must be linear (wave base + lane*16)
#define GLD16(gp, lp)                                                   \
  __builtin_amdgcn_global_load_lds(                                     \
      (const __attribute__((address_space(1))) void*)(gp),              \
      (__attribute__((address_space(3))) void*)(lp), 16, 0, 0)

// Q scale: softmax uses exp2, so fold log2(e) into the 1/sqrt(64) scale
#define QSCALE 0.18033688011112042f

// ---------------- fused fp32 -> bf16 convert (x | w_qkv | w_proj) ----------------
__global__ __launch_bounds__(256) void cvt_all(
    const float* __restrict__ x, const float* __restrict__ wq, const float* __restrict__ wp,
    short* __restrict__ xb, short* __restrict__ wqb, short* __restrict__ wpb) {
  int i = blockIdx.x * 256 + threadIdx.x;  // in float4 units; total 2097152
  const float* s; short* d; int off;
  if (i < 1048576)      { s = x;  d = xb;  off = i; }
  else if (i < 1835008) { s = wq; d = wqb; off = i - 1048576; }
  else                  { s = wp; d = wpb; off = i - 1835008; }
  float4v v = ((const float4v*)s)[off];
  short4v o;
  o.x = f2bf(v.x); o.y = f2bf(v.y); o.z = f2bf(v.z); o.w = f2bf(v.w);
  ((short4v*)d)[off] = o;
}

// ---------------- GEMM: C[M,Ncols] = A[M,1024] @ Bw[Ncols,1024]^T + bias ----------------
// Depth-2 prefetch with counted vmcnt (T4, proven R9).
template <int MODE>
__global__ __launch_bounds__(256) void gemm_bt(
    const short* __restrict__ A, const short* __restrict__ Bw,
    const float* __restrict__ bias,
    short* __restrict__ qo, short* __restrict__ ko, short* __restrict__ vto,
    float* __restrict__ outf) {
  __shared__ short As[2][128 * 64];
  __shared__ short Bs[2][128 * 64];
  const int t = threadIdx.x;
  const int lane = t & 63, wid = t >> 6;
  const int g = lane >> 4, l15 = lane & 15;
  const int wr = (wid >> 1) * 64, wc = (wid & 1) * 64;
  const int bm0 = blockIdx.y * 128, bn0 = blockIdx.x * 128;

  const int sr = t >> 3;
  const int ssub0 = t & 7;

  // LICM: swizzled fragment offsets (row&7 == l15&7 -> uniform swizzle term)
  const int swz = (l15 & 7) << 4;
  int aoff[2][4], boff[2][4];
#pragma unroll
  for (int kk = 0; kk < 2; ++kk)
#pragma unroll
    for (int f = 0; f < 4; ++f) {
      aoff[kk][f] = ((wr + f * 16 + l15) * 128 + kk * 64 + g * 16) ^ swz;
      boff[kk][f] = ((wc + f * 16 + l15) * 128 + kk * 64 + g * 16) ^ swz;
    }

  f32x4 acc[4][4] = {};

  auto stage = [&](int buf, int k0) {
#pragma unroll
    for (int i = 0; i < 4; ++i) {
      int row = i * 32 + sr;
      int s = ssub0 ^ (row & 7);
      char* ldsA = (char*)&As[buf][0] + (i * 256 + (t & ~63)) * 16;
      char* ldsB = (char*)&Bs[buf][0] + (i * 256 + (t & ~63)) * 16;
      GLD16(A + (size_t)(bm0 + row) * 1024 + k0 + s * 8, ldsA);
      GLD16(Bw + (size_t)(bn0 + row) * 1024 + k0 + s * 8, ldsB);
    }
  };

  stage(0, 0);    // prefetch K-tile 0 (8 loads)
  stage(1, 64);   // prefetch K-tile 1 (8 more; 16 in flight)
  int curOff = 0;

  for (int it = 0; it < 16; ++it) {
    // wait for THIS tile's 8 loads (oldest in FIFO); keep next tile's in flight
    if (it == 15) asm volatile("s_waitcnt vmcnt(0)" ::: "memory");
    else          asm volatile("s_waitcnt vmcnt(8)" ::: "memory");
    __builtin_amdgcn_s_barrier();          // all waves: tile `it` ready
    __builtin_amdgcn_sched_barrier(0);
    const char* AsB = (const char*)&As[0][0] + curOff;
    const char* BsB = (const char*)&Bs[0][0] + curOff;
#pragma unroll
    for (int kk = 0; kk < 2; ++kk) {
      short8 a[4], b[4];
#pragma unroll
      for (int mi = 0; mi < 4; ++mi) a[mi] = *(const short8*)(AsB + aoff[kk][mi]);
#pragma unroll
      for (int ni = 0; ni < 4; ++ni) b[ni] = *(const short8*)(BsB + boff[kk][ni]);
#pragma unroll
      for (int mi = 0; mi < 4; ++mi)
#pragma unroll
        for (int ni = 0; ni < 4; ++ni)
          acc[mi][ni] = __builtin_amdgcn_mfma_f32_16x16x32_bf16(a[mi], b[ni], acc[mi][ni], 0, 0, 0);
    }
    __builtin_amdgcn_sched_barrier(0);     // pin all reads before the barrier
    __builtin_amdgcn_s_barrier();          // all waves done reading this buffer
    __builtin_amdgcn_sched_barrier(0);     // pin stage after the barrier
    if (it + 2 < 16) stage(it & 1, (it + 2) * 64);  // (it+2)&1 == it&1
    curOff ^= 16384;  // bytes per buffer (128*64*2)
  }

  if constexpr (MODE == 0) {
    const int which = bn0 >> 10;  // block-uniform: 0=Q, 1=K, 2=V
    if (which == 2) {
      // V^T permuted store, vectorized: 4 consecutive n in-lane -> 8B stores
#pragma unroll
      for (int mi = 0; mi < 4; ++mi) {
#pragma unroll
        for (int ni = 0; ni < 4; ++ni) {
          int gcol = bn0 + wc + ni * 16 + l15;
          int w1 = gcol & 1023;
          int h = w1 >> 6, dd = w1 & 63;
          float bv = bias[gcol];
          int grow0 = bm0 + wr + mi * 16 + g * 4;
          int b_ = grow0 >> 11, n0 = grow0 & 2047;
          int bh = b_ * 16 + h;
          int nl = n0 & 63;
          // kv bit-perm [b5][b3][b2][b4][b1][b0]; n0 4-aligned -> np0 too
          int np = (n0 & ~63) | (nl & 32) | ((nl & 12) << 1) | ((nl & 16) >> 2);
          int2v pk;
          pk.x = (int)cvtpk_bf16(acc[mi][ni][0] + bv, acc[mi][ni][1] + bv);
          pk.y = (int)cvtpk_bf16(acc[mi][ni][2] + bv, acc[mi][ni][3] + bv);
          *(int2v*)(vto + ((size_t)bh * 64 + dd) * 2048 + np) = pk;
        }
      }
    } else {
      short* dst = (which == 0) ? qo : ko;
      const float sc = (which == 0) ? QSCALE : 1.0f;
#pragma unroll
      for (int mi = 0; mi < 4; ++mi) {
#pragma unroll
        for (int ni = 0; ni < 4; ++ni) {
          int gcol = bn0 + wc + ni * 16 + l15;
          int w1 = gcol & 1023;
          int h = w1 >> 6, dd = w1 & 63;
          float bv = bias[gcol];
#pragma unroll
          for (int r = 0; r < 4; ++r) {
            int grow = bm0 + wr + mi * 16 + g * 4 + r;
            int b_ = grow >> 11, n = grow & 2047;
            int bh = b_ * 16 + h;
            dst[((size_t)bh * 2048 + n) * 64 + dd] = f2bf((acc[mi][ni][r] + bv) * sc);
          }
        }
      }
    }
  } else {
#pragma unroll
    for (int mi = 0; mi < 4; ++mi) {
#pragma unroll
      for (int ni = 0; ni < 4; ++ni) {
        int gcol = bn0 + wc + ni * 16 + l15;
        float bv = bias[gcol];
#pragma unroll
        for (int r = 0; r < 4; ++r) {
          int grow = bm0 + wr + mi * 16 + g * 4 + r;
          outf[(size_t)grow * 1024 + gcol] = acc[mi][ni][r] + bv;
        }
      }
    }
  }
}

// ---------------- flash attention, swapped-operand, zero-shuffle PV ----------------
// R6 wave config (4 waves x 32 q-rows, grid 512, 2 blocks/CU, XCD-affine
// bh=bid&31) + R9's proven counted-vmcnt phase schedule: each phase covers
// TWO 64-KV sub-tiles in one barrier-free region (independent QK/softmax/PV
// streams -> MFMA/VALU overlap), depth-2 phase prefetch, vmcnt(8) waits.
__global__ __launch_bounds__(256, 2) void attn_fused(
    const short* __restrict__ Qg, const short* __restrict__ Kg,
    const short* __restrict__ Vtg, short* __restrict__ AO) {
  __shared__ short Ks[4][64 * 64];  // slot = buf*2 + sub, 8KB each
  __shared__ short Vs[4][64 * 64];
  const int bid = blockIdx.x;
  const int bh = bid & 31, qt = bid >> 5;
  const int t = threadIdx.x, wid = t >> 6, lane = t & 63;
  const int g = lane >> 4, l15 = lane & 15;
  const int q0w = qt * 128 + wid * 32;
  const short* qb = Qg + ((size_t)bh * 2048 + q0w) * 64;
  const short* kb = Kg + (size_t)bh * 2048 * 64;
  const short* vb = Vtg + (size_t)bh * 64 * 2048;

  // staging: linear LDS dest, pre-swizzled global source (rule 21)
  const int srow = t >> 3;
  const int ssub = (t & 7) ^ (srow & 7);
  const short* ksrc0 = kb + srow * 64 + ssub * 8;
  const short* vsrc0 = vb + (size_t)srow * 2048 + ssub * 8;

  // LICM: swizzled fragment offsets, shared by K and V reads
  const int swz = (l15 & 7) << 4;
  int foff[2][4];
#pragma unroll
  for (int kk = 0; kk < 2; ++kk)
#pragma unroll
    for (int f = 0; f < 4; ++f)
      foff[kk][f] = ((f * 16 + l15) * 128 + kk * 64 + g * 16) ^ swz;

  short8 bq[2][2];
#pragma unroll
  for (int qf = 0; qf < 2; ++qf)
#pragma unroll
    for (int kk = 0; kk < 2; ++kk)
      bq[qf][kk] = *(const short8*)(qb + (qf * 16 + l15) * 64 + kk * 32 + g * 8);

  // stage one phase = 2 sub-tiles (8 GLD16/thread)
  auto stageP = [&](int buf, int p) {
    const int n0 = p * 128;
#pragma unroll
    for (int sub = 0; sub < 2; ++sub) {
      const int nn = n0 + sub * 64;
      char* ldsK = (char*)&Ks[buf * 2 + sub][0] + wid * 1024;
      char* ldsV = (char*)&Vs[buf * 2 + sub][0] + wid * 1024;
#pragma unroll
      for (int i = 0; i < 2; ++i) {
        GLD16(ksrc0 + (size_t)(nn + i * 32) * 64, ldsK + i * 4096);
        GLD16(vsrc0 + (size_t)i * 32 * 2048 + nn, ldsV + i * 4096);
      }
    }
  };

  stageP(0, 0);  // 8 loads
  stageP(1, 1);  // 16 in flight

  f32x4 acc[2][4] = {};
  float mrun[2] = {-3.0e38f, -3.0e38f}, lrun[2] = {0.f, 0.f};

  for (int p = 0; p < 16; ++p) {
    // oldest 8 loads = this phase's 2 sub-tiles; keep next phase's in flight
    if (p == 15) asm volatile("s_waitcnt vmcnt(0)" ::: "memory");
    else         asm volatile("s_waitcnt vmcnt(8)" ::: "memory");
    __builtin_amdgcn_s_barrier();
    __builtin_amdgcn_sched_barrier(0);
    const int buf = p & 1;

#pragma unroll
    for (int sub = 0; sub < 2; ++sub) {
      const char* KsB = (const char*)&Ks[buf * 2 + sub][0];
      const char* VsB = (const char*)&Vs[buf * 2 + sub][0];

      // S^T[kv][q]: s[qf][kf], kv = kf*16 + g*4 + r, q = qf*16 + l15
      f32x4 s[2][4] = {};
#pragma unroll
      for (int kk = 0; kk < 2; ++kk) {
        short8 ak[4];
#pragma unroll
        for (int kf = 0; kf < 4; ++kf) ak[kf] = *(const short8*)(KsB + foff[kk][kf]);
#pragma unroll
        for (int kf = 0; kf < 4; ++kf)
#pragma unroll
          for (int qf = 0; qf < 2; ++qf)
            s[qf][kf] = __builtin_amdgcn_mfma_f32_16x16x32_bf16(ak[kf], bq[qf][kk], s[qf][kf], 0, 0, 0);
      }

      // tile max per qf
      float pm[2];
#pragma unroll
      for (int qf = 0; qf < 2; ++qf) {
        float m0 = fmaxf(s[qf][0][0], s[qf][0][1]);
        m0 = fmaxf(fmaxf(m0, s[qf][0][2]), s[qf][0][3]);
#pragma unroll
        for (int kf = 1; kf < 4; ++kf) {
          m0 = fmaxf(fmaxf(m0, s[qf][kf][0]), s[qf][kf][1]);
          m0 = fmaxf(fmaxf(m0, s[qf][kf][2]), s[qf][kf][3]);
        }
        float x = fmaxf(m0, __shfl_xor(m0, 16));
        pm[qf] = fmaxf(x, __shfl_xor(x, 32));
      }

      // defer-max (T13)
      if (!__all((pm[0] - mrun[0] <= 8.f) && (pm[1] - mrun[1] <= 8.f))) {
#pragma unroll
        for (int qf = 0; qf < 2; ++qf) {
          float mn = fmaxf(mrun[qf], pm[qf]);
          float alpha = __builtin_amdgcn_exp2f(mrun[qf] - mn);
          mrun[qf] = mn;
          lrun[qf] *= alpha;
#pragma unroll
          for (int df = 0; df < 4; ++df)
#pragma unroll
            for (int r = 0; r < 4; ++r) acc[qf][df][r] *= alpha;
        }
      }

      // P = exp2(S - m), row sums, pack to bf16 pairs (lane-local)
      unsigned wpk[2][4][2];
#pragma unroll
      for (int qf = 0; qf < 2; ++qf) {
        float rs = 0.f;
        float pp[4][4];
#pragma unroll
        for (int kf = 0; kf < 4; ++kf)
#pragma unroll
          for (int r = 0; r < 4; ++r) {
            pp[kf][r] = __builtin_amdgcn_exp2f(s[qf][kf][r] - mrun[qf]);
            rs += pp[kf][r];
          }
        rs += __shfl_xor(rs, 16);
        rs += __shfl_xor(rs, 32);
        lrun[qf] += rs;
#pragma unroll
        for (int kf = 0; kf < 4; ++kf)
#pragma unroll
          for (int h = 0; h < 2; ++h)
            wpk[qf][kf][h] = cvtpk_bf16(pp[kf][2 * h], pp[kf][2 * h + 1]);
      }

      // O^T += V^T_perm @ P^T — B operand is the lane's own packed words
#pragma unroll
      for (int kk = 0; kk < 2; ++kk) {
        short8 av[4];
#pragma unroll
        for (int df = 0; df < 4; ++df) av[df] = *(const short8*)(VsB + foff[kk][df]);
#pragma unroll
        for (int qf = 0; qf < 2; ++qf) {
          union { int4v i; short8 s; } pv;
          pv.i[0] = (int)wpk[qf][2 * kk][0];
          pv.i[1] = (int)wpk[qf][2 * kk][1];
          pv.i[2] = (int)wpk[qf][2 * kk + 1][0];
          pv.i[3] = (int)wpk[qf][2 * kk + 1][1];
#pragma unroll
          for (int df = 0; df < 4; ++df)
            acc[qf][df] = __builtin_amdgcn_mfma_f32_16x16x32_bf16(av[df], pv.s, acc[qf][df], 0, 0, 0);
        }
      }
    }

    __builtin_amdgcn_sched_barrier(0);  // pin reads before the barrier
    __builtin_amdgcn_s_barrier();       // all waves done reading this buf
    __builtin_amdgcn_sched_barrier(0);  // pin stage after the barrier
    if (p + 2 < 16) stageP(buf, p + 2);
  }

  // O^T fragments: d = df*16 + g*4 + r, q = q0w + qf*16 + l15
  const int b_ = bh >> 4, h = bh & 15;
#pragma unroll
  for (int qf = 0; qf < 2; ++qf) {
    const float inv = 1.0f / lrun[qf];
    short* outp = AO + ((size_t)b_ * 2048 + q0w + qf * 16 + l15) * 1024 + h * 64 + g * 4;
#pragma unroll
    for (int df = 0; df < 4; ++df) {
      short4v o;
#pragma unroll
      for (int r = 0; r < 4; ++r) o[r] = f2bf(acc[qf][df][r] * inv);
      *(short4v*)(outp + df * 16) = o;
    }
  }
}

// ---------------- launch ----------------
extern "C" void kernel_launch(void* const* d_in, const int* in_sizes, int n_in,
                              void* d_out, int out_size, void* d_ws, size_t ws_size,
                              hipStream_t stream) {
  const float* x = (const float*)d_in[0];
  const float* w_qkv = (const float*)d_in[1];
  const float* b_qkv = (const float*)d_in[2];
  const float* w_proj = (const float*)d_in[3];
  const float* b_proj = (const float*)d_in[4];
  float* out = (float*)d_out;
  char* ws = (char*)d_ws;

  short* xb    = (short*)(ws + (size_t)0);
  short* wqkvb = (short*)(ws + ((size_t)8 << 20));
  short* wprojb= (short*)(ws + ((size_t)14 << 20));
  short* qb    = (short*)(ws + ((size_t)16 << 20));
  short* kb    = (short*)(ws + ((size_t)24 << 20));
  short* vtb   = (short*)(ws + ((size_t)32 << 20));
  short* aob   = (short*)(ws + ((size_t)40 << 20));

  cvt_all<<<8192, 256, 0, stream>>>(x, w_qkv, w_proj, xb, wqkvb, wprojb);
  gemm_bt<0><<<dim3(24, 32), 256, 0, stream>>>(xb, wqkvb, b_qkv, qb, kb, vtb, nullptr);
  attn_fused<<<512, 256, 0, stream>>>(qb, kb, vtb, aob);
  gemm_bt<1><<<dim3(8, 32), 256, 0, stream>>>(aob, wprojb, b_proj, nullptr, nullptr, nullptr, out);
}